// Round 1
// baseline (1118.576 us; speedup 1.0000x reference)
//
#include <hip/hip_runtime.h>
#include <stdint.h>

// Problem constants: B=64, T=64, C=4096, H=64, hd=64, rank=1, scale=0.125
#define M_TOK   4096      // B*T
#define C_DIM   4096
#define N_QKV   12288

typedef __bf16 bf16x8 __attribute__((ext_vector_type(8)));
typedef float  f32x4  __attribute__((ext_vector_type(4)));

__device__ __forceinline__ unsigned short f2bf(float f) {
  unsigned int u = __builtin_bit_cast(unsigned int, f);
  u = (u + 0x7FFFu + ((u >> 16) & 1u)) >> 16;   // RNE
  return (unsigned short)u;
}
__device__ __forceinline__ float bf2f(unsigned short h) {
  unsigned int u = ((unsigned int)h) << 16;
  return __builtin_bit_cast(float, u);
}

// ---------------- fp32 -> bf16 conversion (16B out per thread) ----------------
__global__ __launch_bounds__(256) void cvt_f32_bf16(const float* __restrict__ in,
                                                    unsigned short* __restrict__ out,
                                                    int n16) {  // n16 = elems/8
  int idx = blockIdx.x * 256 + threadIdx.x;
  if (idx >= n16) return;
  const float4* p = (const float4*)in;
  float4 a = p[idx * 2], b = p[idx * 2 + 1];
  uint4 r;
  r.x = (unsigned)f2bf(a.x) | ((unsigned)f2bf(a.y) << 16);
  r.y = (unsigned)f2bf(a.z) | ((unsigned)f2bf(a.w) << 16);
  r.z = (unsigned)f2bf(b.x) | ((unsigned)f2bf(b.y) << 16);
  r.w = (unsigned)f2bf(b.z) | ((unsigned)f2bf(b.w) << 16);
  ((uint4*)out)[idx] = r;
}

// ---------------- NT bf16 GEMM: C[M,N] = A[M,K] * B[N,K]^T + bias[N] ----------
// 128x128 tile, BK=32, 256 threads (4 waves, each 64x64 = 4x4 mfma 16x16x32 tiles)
#define GLLDS(gp, lp) \
  __builtin_amdgcn_global_load_lds((const __attribute__((address_space(1))) unsigned int*)(gp), \
                                   (__attribute__((address_space(3))) unsigned int*)(lp), 16, 0, 0)

template <int OUT_BF16>
__global__ __launch_bounds__(256, 3) void gemm_bt(const unsigned short* __restrict__ A,
                                                  const unsigned short* __restrict__ B,
                                                  const float* __restrict__ bias,
                                                  void* __restrict__ Cptr,
                                                  int M, int N, int K) {
  __shared__ __align__(16) unsigned short As[128 * 32];
  __shared__ __align__(16) unsigned short Bs[128 * 32];

  const int t  = threadIdx.x;
  const int bm = blockIdx.y;
  const int bn = blockIdx.x;
  const int w  = t >> 6;
  const int l  = t & 63;
  const int wm = (w >> 1) * 64;        // wave quadrant
  const int wn = (w & 1) * 64;
  const int lr = l & 15;               // row/col within a 16-tile
  const int lk = (l >> 4) * 8;         // k-chunk start (elements)

  // staging: thread t loads 16B chunks t and t+256 of each 128x32 tile
  const int srow = t >> 2;
  const int scol = (t & 3) * 8;
  const unsigned short* ga0 = A + (size_t)(bm * 128 + srow) * K + scol;
  const unsigned short* ga1 = ga0 + (size_t)64 * K;
  const unsigned short* gb0 = B + (size_t)(bn * 128 + srow) * K + scol;
  const unsigned short* gb1 = gb0 + (size_t)64 * K;
  unsigned short* la0 = As + t * 8;          // byte offset t*16 = wave_base + lane*16
  unsigned short* la1 = As + t * 8 + 2048;
  unsigned short* lb0 = Bs + t * 8;
  unsigned short* lb1 = Bs + t * 8 + 2048;

  f32x4 acc[4][4] = {};

  for (int k0 = 0; k0 < K; k0 += 32) {
    GLLDS(ga0, la0);
    GLLDS(ga1, la1);
    GLLDS(gb0, lb0);
    GLLDS(gb1, lb1);
    ga0 += 32; ga1 += 32; gb0 += 32; gb1 += 32;
    __syncthreads();   // drains vmcnt -> staged data visible

    bf16x8 af[4], bf[4];
#pragma unroll
    for (int i = 0; i < 4; ++i)
      af[i] = *(const bf16x8*)(As + (wm + i * 16 + lr) * 32 + lk);
#pragma unroll
    for (int j = 0; j < 4; ++j)
      bf[j] = *(const bf16x8*)(Bs + (wn + j * 16 + lr) * 32 + lk);
#pragma unroll
    for (int i = 0; i < 4; ++i)
#pragma unroll
      for (int j = 0; j < 4; ++j)
        acc[i][j] = __builtin_amdgcn_mfma_f32_16x16x32_bf16(af[i], bf[j], acc[i][j], 0, 0, 0);
    __syncthreads();   // compute done before next stage overwrites LDS
  }

  // epilogue: C/D layout col=lane&15, row=(lane>>4)*4+reg
  const int row0 = bm * 128 + wm + (l >> 4) * 4;
  const int col0 = bn * 128 + wn + lr;
#pragma unroll
  for (int j = 0; j < 4; ++j) {
    const int col = col0 + j * 16;
    const float bv = bias[col];
#pragma unroll
    for (int i = 0; i < 4; ++i) {
      const int row = row0 + i * 16;
#pragma unroll
      for (int rg = 0; rg < 4; ++rg) {
        float v = acc[i][j][rg] + bv;
        if (OUT_BF16)
          ((unsigned short*)Cptr)[(size_t)(row + rg) * N + col] = f2bf(v);
        else
          ((float*)Cptr)[(size_t)(row + rg) * N + col] = v;
      }
    }
  }
}

// ---------------- head-mixing attention, one block per (b,t) ------------------
// qkv row: [q(64x64) | k(64x64) | v(64x64)] bf16. scores across heads,
// causal over head index (j<=i), softmax over j, y = P*V -> bf16.
__global__ __launch_bounds__(256) void attn_kernel(const unsigned short* __restrict__ qkv,
                                                   unsigned short* __restrict__ y) {
  __shared__ __align__(16) unsigned short qkvs[12288];
  __shared__ float att[64 * 64];
  const int t = threadIdx.x;
  const size_t base = (size_t)blockIdx.x * 12288;

  const uint4* g = (const uint4*)(qkv + base);
  uint4* lv = (uint4*)qkvs;
#pragma unroll
  for (int r = 0; r < 6; ++r) lv[t + 256 * r] = g[t + 256 * r];
  __syncthreads();

  const int i = t >> 2;                 // q head handled by this thread group
  unsigned int qp[32];                  // q row cached packed (2 bf16 / uint)
  const unsigned int* qrow = (const unsigned int*)(qkvs) + i * 32;
#pragma unroll
  for (int d = 0; d < 32; ++d) qp[d] = qrow[d];

  for (int j = (t & 3); j < 64; j += 4) {
    if (j <= i) {
      const unsigned int* krow = (const unsigned int*)(qkvs + 4096) + j * 32;
      float acc = 0.f;
#pragma unroll
      for (int d = 0; d < 32; ++d) {
        unsigned int qq = qp[d], kk = krow[d];
        acc += bf2f((unsigned short)qq) * bf2f((unsigned short)kk);
        acc += bf2f((unsigned short)(qq >> 16)) * bf2f((unsigned short)(kk >> 16));
      }
      att[i * 64 + j] = acc * 0.125f;   // scale = 1/sqrt(64) * sqrt(rank=1)
    }
  }
  __syncthreads();

  if (t < 64) {                         // softmax over j<=row
    float mx = -1e30f;
    for (int j = 0; j <= t; ++j) mx = fmaxf(mx, att[t * 64 + j]);
    float s = 0.f;
    for (int j = 0; j <= t; ++j) { float e = __expf(att[t * 64 + j] - mx); att[t * 64 + j] = e; s += e; }
    float inv = 1.f / s;
    for (int j = 0; j <= t; ++j) att[t * 64 + j] *= inv;
  }
  __syncthreads();

  const int d0 = (t & 3) * 16;
  float accv[16];
#pragma unroll
  for (int d = 0; d < 16; ++d) accv[d] = 0.f;
  for (int j = 0; j <= i; ++j) {
    const float p = att[i * 64 + j];
    const unsigned int* vrow = (const unsigned int*)(qkvs + 8192 + j * 64 + d0);
#pragma unroll
    for (int dd = 0; dd < 8; ++dd) {
      unsigned int vv = vrow[dd];
      accv[dd * 2]     += p * bf2f((unsigned short)vv);
      accv[dd * 2 + 1] += p * bf2f((unsigned short)(vv >> 16));
    }
  }
  uint4 o0, o1;
  o0.x = (unsigned)f2bf(accv[0])  | ((unsigned)f2bf(accv[1])  << 16);
  o0.y = (unsigned)f2bf(accv[2])  | ((unsigned)f2bf(accv[3])  << 16);
  o0.z = (unsigned)f2bf(accv[4])  | ((unsigned)f2bf(accv[5])  << 16);
  o0.w = (unsigned)f2bf(accv[6])  | ((unsigned)f2bf(accv[7])  << 16);
  o1.x = (unsigned)f2bf(accv[8])  | ((unsigned)f2bf(accv[9])  << 16);
  o1.y = (unsigned)f2bf(accv[10]) | ((unsigned)f2bf(accv[11]) << 16);
  o1.z = (unsigned)f2bf(accv[12]) | ((unsigned)f2bf(accv[13]) << 16);
  o1.w = (unsigned)f2bf(accv[14]) | ((unsigned)f2bf(accv[15]) << 16);
  uint4* yo = (uint4*)(y + (size_t)blockIdx.x * 4096 + i * 64 + d0);
  yo[0] = o0;
  yo[1] = o1;
}

// ---------------- launch ------------------------------------------------------
extern "C" void kernel_launch(void* const* d_in, const int* in_sizes, int n_in,
                              void* d_out, int out_size, void* d_ws, size_t ws_size,
                              hipStream_t stream) {
  const float* x  = (const float*)d_in[0];   // (64,64,4096)
  const float* Wa = (const float*)d_in[1];   // (12288,4096)
  const float* ba = (const float*)d_in[2];   // (12288)
  const float* Wp = (const float*)d_in[3];   // (4096,4096)
  const float* bp = (const float*)d_in[4];   // (4096)
  float* out = (float*)d_out;                // (64,64,4096) fp32

  // workspace layout (ushort elems), regions reused across phases:
  //  A: [0, 16.8M)    xb, later Wpb
  //  B: [16.8M, 67M)  Wab, later yb
  //  C: [67M, 117M)   qkvb
  unsigned short* regA = (unsigned short*)d_ws;                 // 33.5 MB
  unsigned short* regB = regA + (size_t)16777216;               // 100.7 MB
  unsigned short* regC = regB + (size_t)50331648;               // 100.7 MB
  unsigned short* xb   = regA;
  unsigned short* Wab  = regB;
  unsigned short* qkvb = regC;
  unsigned short* Wpb  = regA;   // reuse after GEMM1 consumed xb
  unsigned short* yb   = regB;   // reuse after GEMM1 consumed Wab

  cvt_f32_bf16<<<(16777216 / 8) / 256, 256, 0, stream>>>(x, xb, 16777216 / 8);
  cvt_f32_bf16<<<(50331648 / 8) / 256, 256, 0, stream>>>(Wa, Wab, 50331648 / 8);

  // qkv = x @ Wa^T + ba   (M=4096, N=12288, K=4096), bf16 out
  gemm_bt<1><<<dim3(N_QKV / 128, M_TOK / 128), 256, 0, stream>>>(
      xb, Wab, ba, (void*)qkvb, M_TOK, N_QKV, C_DIM);

  cvt_f32_bf16<<<(16777216 / 8) / 256, 256, 0, stream>>>(Wp, Wpb, 16777216 / 8);

  attn_kernel<<<M_TOK, 256, 0, stream>>>(qkvb, yb);

  // out = y @ Wp^T + bp   (M=4096, N=4096, K=4096), fp32 out
  gemm_bt<0><<<dim3(C_DIM / 128, M_TOK / 128), 256, 0, stream>>>(
      yb, Wpb, bp, (void*)out, M_TOK, C_DIM, C_DIM);
}

// Round 3
// 1054.053 us; speedup vs baseline: 1.0612x; 1.0612x over previous
//
#include <hip/hip_runtime.h>
#include <stdint.h>

// Problem constants: B=64, T=64, C=4096, H=64, hd=64, rank=1, scale=0.125
#define M_TOK   4096      // B*T
#define C_DIM   4096
#define N_QKV   12288

typedef __bf16 bf16x8 __attribute__((ext_vector_type(8)));
typedef float  f32x4  __attribute__((ext_vector_type(4)));
typedef unsigned short ushort8 __attribute__((ext_vector_type(8)));

__device__ __forceinline__ unsigned short f2bf(float f) {
  unsigned int u = __builtin_bit_cast(unsigned int, f);
  u = (u + 0x7FFFu + ((u >> 16) & 1u)) >> 16;   // RNE
  return (unsigned short)u;
}
__device__ __forceinline__ float bf2f(unsigned short h) {
  unsigned int u = ((unsigned int)h) << 16;
  return __builtin_bit_cast(float, u);
}

// ---------------- fp32 -> bf16 conversion (16B out per thread) ----------------
__global__ __launch_bounds__(256) void cvt_f32_bf16(const float* __restrict__ in,
                                                    unsigned short* __restrict__ out,
                                                    int n16) {  // n16 = elems/8
  int idx = blockIdx.x * 256 + threadIdx.x;
  if (idx >= n16) return;
  const float4* p = (const float4*)in;
  float4 a = p[idx * 2], b = p[idx * 2 + 1];
  uint4 r;
  r.x = (unsigned)f2bf(a.x) | ((unsigned)f2bf(a.y) << 16);
  r.y = (unsigned)f2bf(a.z) | ((unsigned)f2bf(a.w) << 16);
  r.z = (unsigned)f2bf(b.x) | ((unsigned)f2bf(b.y) << 16);
  r.w = (unsigned)f2bf(b.z) | ((unsigned)f2bf(b.w) << 16);
  ((uint4*)out)[idx] = r;
}

// ---------------- NT bf16 GEMM: C[M,N] = A[M,K] * B[N,K]^T + bias[N] ----------
// 128x128 tile, BK=32, 256 threads (4 waves, each 64x64 = 4x4 mfma 16x16x32 tiles)
// LDS bank-conflict fix: 16B chunks XOR-swizzled by ((row>>1)&3). The swizzle is
// applied on the GLOBAL source side (global_load_lds's LDS dest is lane-fixed),
// and undone on the frag-read side.
#define GLLDS(gp, lp) \
  __builtin_amdgcn_global_load_lds((const __attribute__((address_space(1))) unsigned int*)(gp), \
                                   (__attribute__((address_space(3))) unsigned int*)(lp), 16, 0, 0)

template <int OUT_BF16>
__global__ __launch_bounds__(256, 3) void gemm_bt(const unsigned short* __restrict__ A,
                                                  const unsigned short* __restrict__ B,
                                                  const float* __restrict__ bias,
                                                  void* __restrict__ Cptr,
                                                  int M, int N, int K) {
  __shared__ __align__(16) unsigned short As[128 * 32];
  __shared__ __align__(16) unsigned short Bs[128 * 32];

  const int t  = threadIdx.x;
  const int bm = blockIdx.y;
  const int bn = blockIdx.x;
  const int w  = t >> 6;
  const int l  = t & 63;
  const int wm = (w >> 1) * 64;        // wave quadrant
  const int wn = (w & 1) * 64;
  const int lr = l & 15;               // row/col within a 16-tile
  // swizzled k-chunk for frag reads: chunk' = (l>>4) ^ ((lr>>1)&3)
  const int lk = ((l >> 4) ^ ((lr >> 1) & 3)) * 8;

  // staging: thread t fills LDS slot t (16B). Slot (row=t>>2, c=t&3) receives
  // global chunk q = c ^ ((row>>1)&3) = (t&3) ^ ((t>>3)&3).
  const int srow = t >> 2;
  const int scol = ((t & 3) ^ ((t >> 3) & 3)) * 8;
  const unsigned short* ga0 = A + (size_t)(bm * 128 + srow) * K + scol;
  const unsigned short* ga1 = ga0 + (size_t)64 * K;
  const unsigned short* gb0 = B + (size_t)(bn * 128 + srow) * K + scol;
  const unsigned short* gb1 = gb0 + (size_t)64 * K;
  unsigned short* la0 = As + t * 8;          // byte offset t*16 = wave_base + lane*16
  unsigned short* la1 = As + t * 8 + 2048;
  unsigned short* lb0 = Bs + t * 8;
  unsigned short* lb1 = Bs + t * 8 + 2048;

  f32x4 acc[4][4] = {};

  for (int k0 = 0; k0 < K; k0 += 32) {
    GLLDS(ga0, la0);
    GLLDS(ga1, la1);
    GLLDS(gb0, lb0);
    GLLDS(gb1, lb1);
    ga0 += 32; ga1 += 32; gb0 += 32; gb1 += 32;
    __syncthreads();   // drains vmcnt -> staged data visible

    bf16x8 af[4], bf[4];
#pragma unroll
    for (int i = 0; i < 4; ++i)
      af[i] = *(const bf16x8*)(As + (wm + i * 16 + lr) * 32 + lk);
#pragma unroll
    for (int j = 0; j < 4; ++j)
      bf[j] = *(const bf16x8*)(Bs + (wn + j * 16 + lr) * 32 + lk);
#pragma unroll
    for (int i = 0; i < 4; ++i)
#pragma unroll
      for (int j = 0; j < 4; ++j)
        acc[i][j] = __builtin_amdgcn_mfma_f32_16x16x32_bf16(af[i], bf[j], acc[i][j], 0, 0, 0);
    __syncthreads();   // compute done before next stage overwrites LDS
  }

  // epilogue: C/D layout col=lane&15, row=(lane>>4)*4+reg
  const int row0 = bm * 128 + wm + (l >> 4) * 4;
  const int col0 = bn * 128 + wn + lr;
#pragma unroll
  for (int j = 0; j < 4; ++j) {
    const int col = col0 + j * 16;
    const float bv = bias[col];
#pragma unroll
    for (int i = 0; i < 4; ++i) {
      const int row = row0 + i * 16;
#pragma unroll
      for (int rg = 0; rg < 4; ++rg) {
        float v = acc[i][j][rg] + bv;
        if (OUT_BF16)
          ((unsigned short*)Cptr)[(size_t)(row + rg) * N + col] = f2bf(v);
        else
          ((float*)Cptr)[(size_t)(row + rg) * N + col] = v;
      }
    }
  }
}

// ---------------- head-mixing attention, MFMA, one WAVE per (b,t) -------------
// Per (b,t): S = Q K^T * 0.125 (64x64x64), causal mask over head idx (col<=row),
// softmax over cols, Y = P V. Q frags direct from global; K,V staged in LDS
// (padded stride 72 elems = 144B, 16B-aligned, breaks the 128B bank wrap);
// P round-trips through the K slab (K dead after QK). V^T B-frags via scalar
// u16 gather (one-time cost). All softmax reductions in-register via shfl_xor
// within 16-lane groups (C-layout: row=(l>>4)*4+rg, col=l&15 per 16x16 tile).
#define AST 72   // padded LDS row stride (elements)

__global__ __launch_bounds__(64) void attn_mfma(const unsigned short* __restrict__ qkv,
                                                unsigned short* __restrict__ y) {
  __shared__ __align__(16) unsigned short Ks[64 * AST];   // K, later P
  __shared__ __align__(16) unsigned short Vs[64 * AST];
  const int l  = threadIdx.x;
  const int lr = l & 15;
  const int lq = l >> 4;
  const size_t base = (size_t)blockIdx.x * 12288;

  // ---- stage K,V (coalesced 16B loads, padded LDS rows) ----
  {
    const int jr = l >> 3;          // 0..7
    const int cc = (l & 7) * 8;     // col chunk (elements)
#pragma unroll
    for (int c = 0; c < 8; ++c) {
      const int j = c * 8 + jr;
      *(uint4*)(Ks + j * AST + cc) = *(const uint4*)(qkv + base + 4096 + (size_t)j * 64 + cc);
      *(uint4*)(Vs + j * AST + cc) = *(const uint4*)(qkv + base + 8192 + (size_t)j * 64 + cc);
    }
  }

  // ---- Q A-frags direct from global: A[m=lr][k=lq*8..+7] per (m-tile, kstep) --
  bf16x8 aq[4][2];
#pragma unroll
  for (int it = 0; it < 4; ++it)
#pragma unroll
    for (int kk = 0; kk < 2; ++kk)
      aq[it][kk] = *(const bf16x8*)(qkv + base + (size_t)(it * 16 + lr) * 64 + kk * 32 + lq * 8);

  __syncthreads();

  // ---- S = Q K^T ----
  f32x4 acc[4][4] = {};
#pragma unroll
  for (int kk = 0; kk < 2; ++kk) {
    bf16x8 bk[4];
#pragma unroll
    for (int jt = 0; jt < 4; ++jt)
      bk[jt] = *(const bf16x8*)(Ks + (jt * 16 + lr) * AST + kk * 32 + lq * 8);
#pragma unroll
    for (int it = 0; it < 4; ++it)
#pragma unroll
      for (int jt = 0; jt < 4; ++jt)
        acc[it][jt] = __builtin_amdgcn_mfma_f32_16x16x32_bf16(aq[it][kk], bk[jt], acc[it][jt], 0, 0, 0);
  }

  // ---- mask + softmax in-register ----
#pragma unroll
  for (int it = 0; it < 4; ++it) {
#pragma unroll
    for (int rg = 0; rg < 4; ++rg) {
      const int row = it * 16 + lq * 4 + rg;
      float mx = -1e30f;
#pragma unroll
      for (int jt = 0; jt < 4; ++jt) {
        const int col = jt * 16 + lr;
        float s = acc[it][jt][rg] * 0.125f;
        s = (col <= row) ? s : -1e30f;
        acc[it][jt][rg] = s;
        mx = fmaxf(mx, s);
      }
#pragma unroll
      for (int d = 1; d < 16; d <<= 1)
        mx = fmaxf(mx, __shfl_xor(mx, d));
      float sum = 0.f;
#pragma unroll
      for (int jt = 0; jt < 4; ++jt) {
        float e = __expf(acc[it][jt][rg] - mx);
        acc[it][jt][rg] = e;
        sum += e;
      }
#pragma unroll
      for (int d = 1; d < 16; d <<= 1)
        sum += __shfl_xor(sum, d);
      const float inv = 1.f / sum;
#pragma unroll
      for (int jt = 0; jt < 4; ++jt)
        acc[it][jt][rg] *= inv;
    }
  }

  // ---- P -> LDS (bf16, row-major stride AST), reusing K slab ----
#pragma unroll
  for (int it = 0; it < 4; ++it)
#pragma unroll
    for (int rg = 0; rg < 4; ++rg) {
      const int row = it * 16 + lq * 4 + rg;
#pragma unroll
      for (int jt = 0; jt < 4; ++jt)
        Ks[row * AST + jt * 16 + lr] = f2bf(acc[it][jt][rg]);
    }
  __syncthreads();

  // ---- Y = P V ----
  f32x4 out[4][4] = {};
#pragma unroll
  for (int kk = 0; kk < 2; ++kk) {
    bf16x8 ap[4];
#pragma unroll
    for (int it = 0; it < 4; ++it)
      ap[it] = *(const bf16x8*)(Ks + (it * 16 + lr) * AST + kk * 32 + lq * 8);
#pragma unroll
    for (int dt = 0; dt < 4; ++dt) {
      ushort8 vt;
#pragma unroll
      for (int jj = 0; jj < 8; ++jj)
        vt[jj] = Vs[(kk * 32 + lq * 8 + jj) * AST + dt * 16 + lr];
      const bf16x8 bv = __builtin_bit_cast(bf16x8, vt);
#pragma unroll
      for (int it = 0; it < 4; ++it)
        out[it][dt] = __builtin_amdgcn_mfma_f32_16x16x32_bf16(ap[it], bv, out[it][dt], 0, 0, 0);
    }
  }

  // ---- epilogue: y[bt][i*64+d] bf16 ----
  unsigned short* yrow = y + (size_t)blockIdx.x * 4096;
#pragma unroll
  for (int it = 0; it < 4; ++it)
#pragma unroll
    for (int rg = 0; rg < 4; ++rg) {
      const int i = it * 16 + lq * 4 + rg;
#pragma unroll
      for (int dt = 0; dt < 4; ++dt)
        yrow[i * 64 + dt * 16 + lr] = f2bf(out[it][dt][rg]);
    }
}

// ---------------- launch ------------------------------------------------------
extern "C" void kernel_launch(void* const* d_in, const int* in_sizes, int n_in,
                              void* d_out, int out_size, void* d_ws, size_t ws_size,
                              hipStream_t stream) {
  const float* x  = (const float*)d_in[0];   // (64,64,4096)
  const float* Wa = (const float*)d_in[1];   // (12288,4096)
  const float* ba = (const float*)d_in[2];   // (12288)
  const float* Wp = (const float*)d_in[3];   // (4096,4096)
  const float* bp = (const float*)d_in[4];   // (4096)
  float* out = (float*)d_out;                // (64,64,4096) fp32

  // workspace layout (ushort elems), regions reused across phases:
  //  A: [0, 16.8M)    xb, later Wpb
  //  B: [16.8M, 67M)  Wab, later yb
  //  C: [67M, 117M)   qkvb
  unsigned short* regA = (unsigned short*)d_ws;                 // 33.5 MB
  unsigned short* regB = regA + (size_t)16777216;               // 100.7 MB
  unsigned short* regC = regB + (size_t)50331648;               // 100.7 MB
  unsigned short* xb   = regA;
  unsigned short* Wab  = regB;
  unsigned short* qkvb = regC;
  unsigned short* Wpb  = regA;   // reuse after GEMM1 consumed xb
  unsigned short* yb   = regB;   // reuse after GEMM1 consumed Wab

  cvt_f32_bf16<<<(16777216 / 8) / 256, 256, 0, stream>>>(x, xb, 16777216 / 8);
  cvt_f32_bf16<<<(50331648 / 8) / 256, 256, 0, stream>>>(Wa, Wab, 50331648 / 8);

  // qkv = x @ Wa^T + ba   (M=4096, N=12288, K=4096), bf16 out
  gemm_bt<1><<<dim3(N_QKV / 128, M_TOK / 128), 256, 0, stream>>>(
      xb, Wab, ba, (void*)qkvb, M_TOK, N_QKV, C_DIM);

  cvt_f32_bf16<<<(16777216 / 8) / 256, 256, 0, stream>>>(Wp, Wpb, 16777216 / 8);

  attn_mfma<<<M_TOK, 64, 0, stream>>>(qkvb, yb);

  // out = y @ Wp^T + bp   (M=4096, N=4096, K=4096), fp32 out
  gemm_bt<0><<<dim3(C_DIM / 128, M_TOK / 128), 256, 0, stream>>>(
      yb, Wpb, bp, (void*)out, M_TOK, C_DIM, C_DIM);
}